// Round 1
// baseline (18279.288 us; speedup 1.0000x reference)
//
#include <hip/hip_runtime.h>
#include <math.h>

#define B_ 4
#define T_ 1024
#define D_ 1024
#define H_ 16
#define DFF_ 4096
#define HD_ 64
#define BT_ (B_*T_)
#define PL ((size_t)BT_*D_)   /* 4M-float component plane */

__device__ __forceinline__ float block_sum(float v, float* sm){
  #pragma unroll
  for (int o=32;o>0;o>>=1) v += __shfl_down(v,o);
  int wid = threadIdx.x>>6;
  if ((threadIdx.x&63)==0) sm[wid]=v;
  __syncthreads();
  float r = sm[0]+sm[1]+sm[2]+sm[3];
  __syncthreads();
  return r;
}
__device__ __forceinline__ float block_max(float v, float* sm){
  #pragma unroll
  for (int o=32;o>0;o>>=1) v = fmaxf(v,__shfl_down(v,o));
  int wid = threadIdx.x>>6;
  if ((threadIdx.x&63)==0) sm[wid]=v;
  __syncthreads();
  float r = fmaxf(fmaxf(sm[0],sm[1]),fmaxf(sm[2],sm[3]));
  __syncthreads();
  return r;
}

// Per-component LayerNorm over D. grid = (BT, 2), block = 256.
__global__ __launch_bounds__(256) void cln_kernel(const float* __restrict__ x,
    const float* __restrict__ g, const float* __restrict__ bb,
    float* __restrict__ out)
{
  __shared__ float sm[4];
  int row = blockIdx.x, comp = blockIdx.y;
  const float* xr = x + (size_t)comp*PL + (size_t)row*D_;
  float* yr = out + (size_t)comp*PL + (size_t)row*D_;
  const float* gv = g + comp*D_;
  const float* bv = bb + comp*D_;
  float v[4]; float s = 0.f;
  #pragma unroll
  for (int i=0;i<4;i++){ v[i] = xr[threadIdx.x + 256*i]; s += v[i]; }
  s = block_sum(s, sm);
  float mean = s * (1.0f/D_);
  float s2 = 0.f;
  #pragma unroll
  for (int i=0;i<4;i++){ float d = v[i]-mean; s2 += d*d; }
  s2 = block_sum(s2, sm);
  float inv = rsqrtf(s2*(1.0f/D_) + 1e-5f);
  #pragma unroll
  for (int i=0;i<4;i++){
    int idx = threadIdx.x + 256*i;
    yr[idx] = (v[i]-mean)*inv*gv[idx] + bv[idx];
  }
}

// Complex GEMM: C = A @ W^T + bias (+residual) (opt CReLU).
// A planes [M,K]; W = [2,N,K]; bias [2,N]; C planes [M,N].
#define BM 64
#define BN 64
#define BK 16
__global__ __launch_bounds__(256) void cgemm_kernel(
    const float* __restrict__ Ar, const float* __restrict__ Ai,
    const float* __restrict__ W, const float* __restrict__ bias,
    const float* __restrict__ Rr, const float* __restrict__ Ri,
    float* __restrict__ Cr, float* __restrict__ Ci,
    int M, int N, int K, int relu)
{
  __shared__ float Asr[BK][BM+4], Asi[BK][BM+4], Bsr[BK][BN+4], Bsi[BK][BN+4];
  const float* Wr = W;
  const float* Wi = W + (size_t)N*K;
  int tid = threadIdx.x;
  int bm = blockIdx.y*BM, bn = blockIdx.x*BN;
  int lr = tid >> 2;          // 0..63
  int lc = (tid & 3) << 2;    // 0,4,8,12
  int ty = tid >> 4, tx = tid & 15;
  float accr[4][4] = {{0.f}}; float acci[4][4] = {{0.f}};
  const float* apr = Ar + (size_t)(bm+lr)*K + lc;
  const float* api = Ai + (size_t)(bm+lr)*K + lc;
  const float* bpr = Wr + (size_t)(bn+lr)*K + lc;
  const float* bpi = Wi + (size_t)(bn+lr)*K + lc;
  for (int k0=0; k0<K; k0+=BK){
    float4 a = *(const float4*)(apr + k0);
    float4 b = *(const float4*)(api + k0);
    float4 c = *(const float4*)(bpr + k0);
    float4 d = *(const float4*)(bpi + k0);
    Asr[lc+0][lr]=a.x; Asr[lc+1][lr]=a.y; Asr[lc+2][lr]=a.z; Asr[lc+3][lr]=a.w;
    Asi[lc+0][lr]=b.x; Asi[lc+1][lr]=b.y; Asi[lc+2][lr]=b.z; Asi[lc+3][lr]=b.w;
    Bsr[lc+0][lr]=c.x; Bsr[lc+1][lr]=c.y; Bsr[lc+2][lr]=c.z; Bsr[lc+3][lr]=c.w;
    Bsi[lc+0][lr]=d.x; Bsi[lc+1][lr]=d.y; Bsi[lc+2][lr]=d.z; Bsi[lc+3][lr]=d.w;
    __syncthreads();
    #pragma unroll
    for (int kk=0; kk<BK; kk++){
      float ar0[4], ai0[4], br0[4], bi0[4];
      #pragma unroll
      for (int i=0;i<4;i++){ ar0[i]=Asr[kk][ty*4+i]; ai0[i]=Asi[kk][ty*4+i]; }
      #pragma unroll
      for (int j=0;j<4;j++){ br0[j]=Bsr[kk][tx*4+j]; bi0[j]=Bsi[kk][tx*4+j]; }
      #pragma unroll
      for (int i=0;i<4;i++){
        #pragma unroll
        for (int j=0;j<4;j++){
          accr[i][j] += ar0[i]*br0[j] - ai0[i]*bi0[j];
          acci[i][j] += ar0[i]*bi0[j] + ai0[i]*br0[j];
        }
      }
    }
    __syncthreads();
  }
  #pragma unroll
  for (int i=0;i<4;i++){
    int m = bm + ty*4 + i;
    #pragma unroll
    for (int j=0;j<4;j++){
      int n = bn + tx*4 + j;
      float cr = accr[i][j] + bias[n];
      float ci = acci[i][j] + bias[N+n];
      if (Rr){ cr += Rr[(size_t)m*N+n]; ci += Ri[(size_t)m*N+n]; }
      if (relu){ cr = fmaxf(cr,0.f); ci = fmaxf(ci,0.f); }
      Cr[(size_t)m*N+n] = cr;
      Ci[(size_t)m*N+n] = ci;
    }
  }
}

// In-place RoPE phasor multiply on Q and K. grid over PL elements.
__global__ __launch_bounds__(256) void rope_kernel(float* __restrict__ Q,
                                                   float* __restrict__ Kk)
{
  size_t idx = (size_t)blockIdx.x*256 + threadIdx.x;   // over PL
  int d = (int)(idx & (HD_-1));
  int t = (int)((idx / D_) & (T_-1));
  float invf = expf(-(float)d * (9.210340371976184f/64.0f)); // 10000^{-d/64}
  float th = (float)t * invf;
  float s, c;
  sincosf(th, &s, &c);
  float qr = Q[idx], qi = Q[PL+idx];
  Q[idx]    = qr*c - qi*s;
  Q[PL+idx] = qr*s + qi*c;
  float kr = Kk[idx], ki = Kk[PL+idx];
  Kk[idx]    = kr*c - ki*s;
  Kk[PL+idx] = kr*s + ki*c;
}

// One block per (query row, head, batch). Streaming causal attention.
__global__ __launch_bounds__(256) void attn_kernel(
    const float* __restrict__ Q, const float* __restrict__ Kk,
    const float* __restrict__ V, float* __restrict__ O)
{
  __shared__ float aw[T_];
  __shared__ float qs[2][HD_];
  __shared__ float sm[4];
  int qt = blockIdx.x, h = blockIdx.y, b = blockIdx.z;
  int tid = threadIdx.x;
  size_t base = (size_t)b*T_*D_ + (size_t)h*HD_;
  const float* qrow = Q + base + (size_t)qt*D_;
  if (tid < HD_){ qs[0][tid] = qrow[tid]; qs[1][tid] = qrow[PL+tid]; }
  __syncthreads();
  float lmax = -1e30f;
  for (int k = tid; k <= qt; k += 256){
    const float4* kr4 = (const float4*)(Kk + base + (size_t)k*D_);
    const float4* ki4 = (const float4*)(Kk + PL + base + (size_t)k*D_);
    float sr = 0.f, si = 0.f;
    #pragma unroll
    for (int d4=0; d4<HD_/4; d4++){
      float4 kr = kr4[d4], ki = ki4[d4];
      const float* qr = &qs[0][d4*4];
      const float* qi = &qs[1][d4*4];
      sr += qr[0]*kr.x + qi[0]*ki.x;  si += qi[0]*kr.x - qr[0]*ki.x;
      sr += qr[1]*kr.y + qi[1]*ki.y;  si += qi[1]*kr.y - qr[1]*ki.y;
      sr += qr[2]*kr.z + qi[2]*ki.z;  si += qi[2]*kr.z - qr[2]*ki.z;
      sr += qr[3]*kr.w + qi[3]*ki.w;  si += qi[3]*kr.w - qr[3]*ki.w;
    }
    float mag = sqrtf(sr*sr + si*si) * 0.125f;  // /sqrt(HD)
    aw[k] = mag;
    lmax = fmaxf(lmax, mag);
  }
  float gmax = block_max(lmax, sm);
  float lsum = 0.f;
  for (int k = tid; k <= qt; k += 256){
    float e = __expf(aw[k] - gmax);
    aw[k] = e; lsum += e;
  }
  float gsum = block_sum(lsum, sm);  // barrier also publishes aw[]
  float inv = 1.0f / gsum;
  if (tid < 128){
    int d = tid & (HD_-1);
    int comp = tid >> 6;
    const float* vp = V + (size_t)comp*PL + base + d;
    float acc = 0.f;
    for (int k=0;k<=qt;k++) acc += aw[k] * vp[(size_t)k*D_];
    O[(size_t)comp*PL + base + (size_t)qt*D_ + d] = acc * inv;
  }
}

// out = z + h * (g / (|g|+1e-8)); chunk of 1024 rows starting at row0.
__global__ __launch_bounds__(256) void gate_kernel(
    const float* __restrict__ z, const float* __restrict__ h,
    const float* __restrict__ g, float* __restrict__ out, int row0)
{
  size_t idx = (size_t)blockIdx.x*256 + threadIdx.x;  // 0..1M
  const size_t CH = (size_t)1024*D_;
  float hr = h[idx], hi = h[CH+idx];
  float gr = g[idx], gi = g[CH+idx];
  float gn = sqrtf(gr*gr + gi*gi) + 1e-8f;
  float pr = (hr*gr - hi*gi) / gn;
  float pi = (hr*gi + hi*gr) / gn;
  size_t zoff = (size_t)row0*D_ + idx;
  out[zoff]    = z[zoff] + pr;
  out[PL+zoff] = z[PL+zoff] + pi;
}

extern "C" void kernel_launch(void* const* d_in, const int* in_sizes, int n_in,
                              void* d_out, int out_size, void* d_ws, size_t ws_size,
                              hipStream_t stream)
{
  const float* x  = (const float*)d_in[0];
  // d_in[1] = mask (deterministic causal tril) — not needed
  const float* wq = (const float*)d_in[2];
  const float* bq = (const float*)d_in[3];
  const float* wk = (const float*)d_in[4];
  const float* bk = (const float*)d_in[5];
  const float* wv = (const float*)d_in[6];
  const float* bv = (const float*)d_in[7];
  const float* wo = (const float*)d_in[8];
  const float* bo = (const float*)d_in[9];
  const float* wf1= (const float*)d_in[10];
  const float* bf1= (const float*)d_in[11];
  const float* wf2= (const float*)d_in[12];
  const float* bf2= (const float*)d_in[13];
  const float* wg = (const float*)d_in[14];
  const float* bg = (const float*)d_in[15];
  const float* g1 = (const float*)d_in[16];
  const float* b1 = (const float*)d_in[17];
  const float* g2 = (const float*)d_in[18];
  const float* b2 = (const float*)d_in[19];
  float* out = (float*)d_out;
  float* ws  = (float*)d_ws;

  const size_t M4 = (size_t)1<<22;   // 4M floats = one component plane
  const size_t M1 = (size_t)1<<20;   // 1M floats
  float* nz  = ws;             // 8M: cln1 out; later reused as attention o
  float* q   = ws + 2*M4;      // 8M: q; later FFN h1 chunk (2 x 4M)
  float* k   = ws + 4*M4;      // 8M: k; later h chunk (2M) + g chunk (2M)
  float* v   = ws + 6*M4;      // 8M: v; later nz2
  float* z   = ws + 8*M4;      // 8M: residual stream after attention
  float* o   = nz;
  float* h1  = q;
  float* hh  = k;
  float* gg  = k + 2*M1;
  float* nz2 = v;

  dim3 blk(256);
  // ---- attention branch ----
  cln_kernel<<<dim3(BT_,2), blk, 0, stream>>>(x, g1, b1, nz);
  dim3 gqkv(D_/BN, BT_/BM);
  cgemm_kernel<<<gqkv, blk, 0, stream>>>(nz, nz+M4, wq, bq, nullptr, nullptr,
                                         q, q+M4, BT_, D_, D_, 0);
  cgemm_kernel<<<gqkv, blk, 0, stream>>>(nz, nz+M4, wk, bk, nullptr, nullptr,
                                         k, k+M4, BT_, D_, D_, 0);
  cgemm_kernel<<<gqkv, blk, 0, stream>>>(nz, nz+M4, wv, bv, nullptr, nullptr,
                                         v, v+M4, BT_, D_, D_, 0);
  rope_kernel<<<dim3((unsigned)(PL/256)), blk, 0, stream>>>(q, k);
  attn_kernel<<<dim3(T_, H_, B_), blk, 0, stream>>>(q, k, v, o);
  cgemm_kernel<<<gqkv, blk, 0, stream>>>(o, o+M4, wo, bo, x, x+M4,
                                         z, z+M4, BT_, D_, D_, 0);
  // ---- FFN branch ----
  cln_kernel<<<dim3(BT_,2), blk, 0, stream>>>(z, g2, b2, nz2);
  for (int c=0; c<4; c++){
    const float* ar = nz2 + (size_t)c*1024*D_;
    cgemm_kernel<<<dim3(DFF_/BN, 1024/BM), blk, 0, stream>>>(
        ar, ar+M4, wf1, bf1, nullptr, nullptr, h1, h1+M4, 1024, DFF_, D_, 1);
    cgemm_kernel<<<dim3(D_/BN, 1024/BM), blk, 0, stream>>>(
        h1, h1+M4, wf2, bf2, nullptr, nullptr, hh, hh+M1, 1024, D_, DFF_, 0);
    cgemm_kernel<<<dim3(D_/BN, 1024/BM), blk, 0, stream>>>(
        hh, hh+M1, wg, bg, nullptr, nullptr, gg, gg+M1, 1024, D_, D_, 0);
    gate_kernel<<<dim3((unsigned)(M1/256)), blk, 0, stream>>>(z, hh, gg, out, c*1024);
  }
}

// Round 3
// 3423.735 us; speedup vs baseline: 5.3390x; 5.3390x over previous
//
#include <hip/hip_runtime.h>
#include <math.h>

#define B_ 4
#define T_ 1024
#define D_ 1024
#define H_ 16
#define DFF_ 4096
#define HD_ 64
#define BT_ (B_*T_)
#define PL ((size_t)BT_*D_)   /* elements per fp32 component plane (4M) */

typedef unsigned int uint;
typedef unsigned short ushort;
typedef __attribute__((ext_vector_type(8))) __bf16 bf16x8;
typedef __attribute__((ext_vector_type(4))) float f32x4;
typedef __attribute__((ext_vector_type(4))) uint uint4v;

__device__ __forceinline__ float b2f(ushort u){
  union{uint i; float f;} x; x.i = ((uint)u)<<16; return x.f;
}
__device__ __forceinline__ ushort f2b(float f){
  union{float f; uint i;} x; x.f = f;
  uint r = x.i + 0x7fffu + ((x.i>>16)&1u);
  return (ushort)(r>>16);
}
__device__ __forceinline__ void fsplit(float x, ushort& hi, ushort& lo){
  hi = f2b(x);
  lo = f2b(x - b2f(hi));   // x - hi exact in fp32
}
__device__ __forceinline__ bf16x8 negv(bf16x8 v){
  union{bf16x8 b; uint4v u;} t; t.b = v;
  t.u ^= 0x80008000u;
  return t.b;
}
__device__ __forceinline__ f32x4 mfma16(bf16x8 a, bf16x8 b, f32x4 c){
  return __builtin_amdgcn_mfma_f32_16x16x32_bf16(a,b,c,0,0,0);
}
__device__ __forceinline__ float block_sum(float v, float* sm){
  #pragma unroll
  for (int o=32;o>0;o>>=1) v += __shfl_down(v,o);
  int wid = threadIdx.x>>6;
  if ((threadIdx.x&63)==0) sm[wid]=v;
  __syncthreads();
  float r = sm[0]+sm[1]+sm[2]+sm[3];
  __syncthreads();
  return r;
}

// fp32 complex weight [2][NK] -> split-bf16 [4][NK] (rh, rl, ih, il)
__global__ __launch_bounds__(256) void cvt_split(const float* __restrict__ s,
                                                 ushort* __restrict__ d, long NK){
  long i = ((long)blockIdx.x*256 + threadIdx.x)*4;
  if (i >= NK) return;
  float4 vr = *(const float4*)(s+i);
  float4 vi = *(const float4*)(s+NK+i);
  ushort4 rh, rl, ih4, il4;
  fsplit(vr.x, rh.x, rl.x); fsplit(vr.y, rh.y, rl.y);
  fsplit(vr.z, rh.z, rl.z); fsplit(vr.w, rh.w, rl.w);
  fsplit(vi.x, ih4.x, il4.x); fsplit(vi.y, ih4.y, il4.y);
  fsplit(vi.z, ih4.z, il4.z); fsplit(vi.w, ih4.w, il4.w);
  *(ushort4*)(d + i)        = rh;
  *(ushort4*)(d + NK + i)   = rl;
  *(ushort4*)(d + 2*NK + i) = ih4;
  *(ushort4*)(d + 3*NK + i) = il4;
}

// Per-component LayerNorm over D; fp32 in, split-bf16 out (4 planes).
// grid (rows, 2). Reads x rows (row0+blockIdx.x), writes local row blockIdx.x.
__global__ __launch_bounds__(256) void cln_kernel(const float* __restrict__ x,
    long PSx, int row0, const float* __restrict__ g, const float* __restrict__ bb,
    ushort* __restrict__ out, long PSo)
{
  __shared__ float sm[4];
  int row = blockIdx.x, comp = blockIdx.y;
  const float* xr = x + (size_t)comp*PSx + (size_t)(row0+row)*D_;
  float4 v = *(const float4*)(xr + threadIdx.x*4);
  float s = v.x+v.y+v.z+v.w;
  s = block_sum(s, sm);
  float mean = s * (1.0f/D_);
  float dx=v.x-mean, dy=v.y-mean, dz=v.z-mean, dw=v.w-mean;
  float s2 = dx*dx+dy*dy+dz*dz+dw*dw;
  s2 = block_sum(s2, sm);
  float inv = 1.0f/sqrtf(s2*(1.0f/D_) + 1e-5f);
  float4 gv = *(const float4*)(g + comp*D_ + threadIdx.x*4);
  float4 bv = *(const float4*)(bb + comp*D_ + threadIdx.x*4);
  float y0 = dx*inv*gv.x + bv.x, y1 = dy*inv*gv.y + bv.y;
  float y2 = dz*inv*gv.z + bv.z, y3 = dw*inv*gv.w + bv.w;
  ushort4 hh, ll;
  fsplit(y0, hh.x, ll.x); fsplit(y1, hh.y, ll.y);
  fsplit(y2, hh.z, ll.z); fsplit(y3, hh.w, ll.w);
  ushort* oh = out + (size_t)(comp*2)*PSo   + (size_t)row*D_;
  ushort* ol = out + (size_t)(comp*2+1)*PSo + (size_t)row*D_;
  *(ushort4*)(oh + threadIdx.x*4) = hh;
  *(ushort4*)(ol + threadIdx.x*4) = ll;
}

// Split-bf16 complex MFMA GEMM: C = A @ W^T + bias (+res) (opt CReLU).
// A: [4][M*K] planes rh,rl,ih,il (stride PSa). W: [4][N*K] (stride PSw),
// +gz*wstride for fused QKV. bias fp32 [2][N] selected by gz.
// Out: fp32 planes Cf (stride PSc, +gz*ostrideF) and/or split-4 Cs (stride PSs).
#define LROW 40
template<int BM,int BN,int WM,int WN>
__global__ __launch_bounds__(256,1) void cgemm_split(
    const ushort* __restrict__ A, long PSa,
    const ushort* __restrict__ W, long PSw, long wstride,
    const float* __restrict__ b0, const float* __restrict__ b1, const float* __restrict__ b2,
    const float* __restrict__ Rr, const float* __restrict__ Ri,
    float* __restrict__ Cf, long PSc, long ostrideF,
    ushort* __restrict__ Cs, long PSs,
    int M, int N, int K, int relu)
{
  constexpr int NI = WM/16, NJ = WN/16;
  constexpr int NWX = BN/WN;
  constexpr int NLOADS = (BM+BN)*16/256;
  __shared__ __align__(16) ushort lds[(BM+BN)*4*LROW];
  const int tid = threadIdx.x, wave = tid>>6, lane = tid&63;
  const int quad = lane>>4, l16 = lane&15;
  const int bm = blockIdx.y*BM, bn = blockIdx.x*BN;
  const int gz = blockIdx.z;
  W += (size_t)gz*wstride;
  const float* bias = (gz==0)? b0 : (gz==1)? b1 : b2;
  if (Cf) Cf += (size_t)gz*ostrideF;
  const int wm = (wave/NWX)*WM, wn = (wave%NWX)*WN;

  f32x4 accr[NI][NJ], acci[NI][NJ];
  #pragma unroll
  for (int i=0;i<NI;i++)
    #pragma unroll
    for (int j=0;j<NJ;j++){
      accr[i][j] = (f32x4){0.f,0.f,0.f,0.f};
      acci[i][j] = (f32x4){0.f,0.f,0.f,0.f};
    }

  for (int k0=0; k0<K; k0+=32){
    __syncthreads();
    #pragma unroll
    for (int r=0;r<NLOADS;r++){
      int id = r*256 + tid;
      const ushort* src; int lrow;
      if (id < 16*BM){
        int pl = id/(4*BM); int rem = id - pl*4*BM;
        int row = rem>>2, sl = rem&3;
        src = A + (size_t)pl*PSa + (size_t)(bm+row)*K + k0 + sl*8;
        lrow = (pl*BM + row)*LROW + sl*8;
      } else {
        int id2 = id - 16*BM;
        int pl = id2/(4*BN); int rem = id2 - pl*4*BN;
        int row = rem>>2, sl = rem&3;
        src = W + (size_t)pl*PSw + (size_t)(bn+row)*K + k0 + sl*8;
        lrow = (4*BM + pl*BN + row)*LROW + sl*8;
      }
      *(uint4*)&lds[lrow] = *(const uint4*)src;
    }
    __syncthreads();
    bf16x8 Bf[NJ][4];
    #pragma unroll
    for (int j=0;j<NJ;j++)
      #pragma unroll
      for (int p=0;p<4;p++)
        Bf[j][p] = *(const bf16x8*)&lds[(4*BM + p*BN + wn + j*16 + l16)*LROW + quad*8];
    #pragma unroll
    for (int i=0;i<NI;i++){
      int ra = (wm + i*16 + l16)*LROW + quad*8;
      bf16x8 A0 = *(const bf16x8*)&lds[(0*BM)*LROW + ra];
      bf16x8 A1 = *(const bf16x8*)&lds[(1*BM)*LROW + ra];
      bf16x8 A2 = *(const bf16x8*)&lds[(2*BM)*LROW + ra];
      bf16x8 A3 = *(const bf16x8*)&lds[(3*BM)*LROW + ra];
      bf16x8 n2 = negv(A2), n3 = negv(A3);
      #pragma unroll
      for (int j=0;j<NJ;j++){
        f32x4 cr = accr[i][j], ci = acci[i][j];
        cr = mfma16(A0, Bf[j][0], cr); cr = mfma16(A0, Bf[j][1], cr); cr = mfma16(A1, Bf[j][0], cr);
        cr = mfma16(n2, Bf[j][2], cr); cr = mfma16(n2, Bf[j][3], cr); cr = mfma16(n3, Bf[j][2], cr);
        ci = mfma16(A0, Bf[j][2], ci); ci = mfma16(A0, Bf[j][3], ci); ci = mfma16(A1, Bf[j][2], ci);
        ci = mfma16(A2, Bf[j][0], ci); ci = mfma16(A2, Bf[j][1], ci); ci = mfma16(A3, Bf[j][0], ci);
        accr[i][j] = cr; acci[i][j] = ci;
      }
    }
  }
  #pragma unroll
  for (int i=0;i<NI;i++){
    #pragma unroll
    for (int j=0;j<NJ;j++){
      #pragma unroll
      for (int rg=0;rg<4;rg++){
        int row = bm + wm + i*16 + quad*4 + rg;
        int col = bn + wn + j*16 + l16;
        float cr = accr[i][j][rg] + bias[col];
        float ci = acci[i][j][rg] + bias[N+col];
        size_t o = (size_t)row*N + col;
        if (Rr){ cr += Rr[o]; ci += Ri[o]; }
        if (relu){ cr = fmaxf(cr,0.f); ci = fmaxf(ci,0.f); }
        if (Cf){ Cf[o] = cr; Cf[PSc + o] = ci; }
        if (Cs){
          ushort h0,l0,h1v,l1;
          fsplit(cr,h0,l0); fsplit(ci,h1v,l1);
          Cs[o] = h0; Cs[PSs+o] = l0; Cs[2*PSs+o] = h1v; Cs[3*PSs+o] = l1;
        }
      }
    }
  }
}

// In-place RoPE on fp32 Q,K chunk planes (PS = plane stride). EXACT round-1 formula.
__global__ __launch_bounds__(256) void rope_kernel(float* __restrict__ Q,
                                                   float* __restrict__ Kk, long PS)
{
  size_t idx = (size_t)blockIdx.x*256 + threadIdx.x;
  int d = (int)(idx & (HD_-1));
  int t = (int)((idx >> 10) & (T_-1));
  float invf = expf(-(float)d * (9.210340371976184f/64.0f));
  float th = (float)t * invf;
  float s, c;
  sincosf(th, &s, &c);
  float qr = Q[idx], qi = Q[PS+idx];
  Q[idx]    = qr*c - qi*s;
  Q[PS+idx] = qr*s + qi*c;
  float kr = Kk[idx], ki = Kk[PS+idx];
  Kk[idx]    = kr*c - ki*s;
  Kk[PS+idx] = kr*s + ki*c;
}

// Flash attention, fp32, QT=8 query rows/block, KT=32 key tile, online softmax.
// grid (32 = b*16+h within chunk of 2 batches, 128 = q-blocks). Output: split-bf16.
#define KT 32
#define KR 140
#define VR 132
__global__ __launch_bounds__(256) void attn_kernel(
    const float* __restrict__ Q, const float* __restrict__ Kp,
    const float* __restrict__ V, long PSq,
    ushort* __restrict__ O, long PSo)
{
  __shared__ __align__(16) float Ks[KT*KR];
  __shared__ __align__(16) float Vs[KT*VR];
  __shared__ __align__(16) float Qs[8*132];
  __shared__ float sc[8*36];
  __shared__ float aw[8*36];
  __shared__ float stm[8], stl[8], sta[8];
  __shared__ float obuf[16*132];
  const int tid = threadIdx.x;
  const int bh = blockIdx.x;
  const int b = bh>>4, h = bh&15;
  const int qb = 127 - blockIdx.y;        // longest-first
  const int qt0 = qb*8;
  // stage Q rows
  {
    int qr = tid>>5, slot = tid&31;
    int comp = slot>>4, c = slot&15;
    size_t g = (size_t)comp*PSq + (size_t)(b*T_ + qt0 + qr)*D_ + h*HD_ + c*4;
    *(float4*)&Qs[qr*132 + comp*64 + c*4] = *(const float4*)(Q + g);
  }
  if (tid < 8){ stm[tid] = -1e30f; stl[tid] = 0.f; }
  float acc[8];
  #pragma unroll
  for (int q=0;q<8;q++) acc[q] = 0.f;
  const int oidx = tid & 127, half = tid>>7;
  const int key = tid>>3, l8 = tid&7;
  const int ntiles = ((qt0+7)>>5) + 1;

  for (int tI=0; tI<ntiles; tI++){
    int kt = tI*KT;
    __syncthreads();
    #pragma unroll
    for (int r=0;r<8;r++){
      int id = r*256 + tid;
      int arr = id>>10;
      int rem = id & 1023;
      int row = rem>>5, slot = rem&31;
      int comp = slot>>4, c = slot&15;
      size_t g = (size_t)comp*PSq + (size_t)(b*T_ + kt + row)*D_ + h*HD_ + c*4;
      float4 v4 = *(const float4*)((arr? V : Kp) + g);
      if (arr) *(float4*)&Vs[row*VR + comp*64 + c*4] = v4;
      else     *(float4*)&Ks[row*KR + comp*64 + c*4] = v4;
    }
    __syncthreads();
    float kr[8], ki[8];
    {
      const float* kp = &Ks[key*KR + l8*8];
      #pragma unroll
      for (int e=0;e<8;e++){ kr[e] = kp[e]; ki[e] = kp[64+e]; }
    }
    #pragma unroll
    for (int qr=0;qr<8;qr++){
      const float* qp = &Qs[qr*132 + l8*8];
      float sr=0.f, si=0.f;
      #pragma unroll
      for (int e=0;e<8;e++){
        float a = qp[e], p = qp[64+e];
        sr += a*kr[e] + p*ki[e];
        si += p*kr[e] - a*ki[e];
      }
      sr += __shfl_xor(sr,1); si += __shfl_xor(si,1);
      sr += __shfl_xor(sr,2); si += __shfl_xor(si,2);
      sr += __shfl_xor(sr,4); si += __shfl_xor(si,4);
      if (l8==0){
        float mag = sqrtf(sr*sr+si*si)*0.125f;
        if (kt+key > qt0+qr) mag = -1e30f;
        sc[qr*36 + key] = mag;
      }
    }
    __syncthreads();
    {
      int w = tid>>6, ln = tid&63;
      if (ln < 32){
        #pragma unroll
        for (int s=0;s<2;s++){
          int qr = w*2+s;
          float mg = sc[qr*36+ln];
          float mx = mg;
          #pragma unroll
          for (int o=16;o>0;o>>=1) mx = fmaxf(mx, __shfl_xor(mx,o));
          float m_old = stm[qr], l_old = stl[qr];
          float m_new = fmaxf(m_old, mx);
          float e = __expf(mg - m_new);
          float se = e;
          #pragma unroll
          for (int o=16;o>0;o>>=1) se += __shfl_xor(se,o);
          aw[qr*36+ln] = e;
          if (ln==0){
            sta[qr] = __expf(m_old - m_new);
            stm[qr] = m_new;
            stl[qr] = l_old*sta[qr] + se;
          }
        }
      }
    }
    __syncthreads();
    {
      float v[16];
      const int kb = half*16;
      #pragma unroll
      for (int kk=0;kk<16;kk++) v[kk] = Vs[(kb+kk)*VR + oidx];
      #pragma unroll
      for (int qr=0;qr<8;qr++){
        float a = acc[qr]*sta[qr];
        #pragma unroll
        for (int kk=0;kk<16;kk++) a += aw[qr*36 + kb+kk] * v[kk];
        acc[qr] = a;
      }
    }
  }
  #pragma unroll
  for (int qr=0;qr<8;qr++) obuf[(half*8+qr)*132 + oidx] = acc[qr];
  __syncthreads();
  if (tid < 128){
    int comp = tid>>6, d = tid&63;
    #pragma unroll
    for (int qr=0;qr<8;qr++){
      float tot = (obuf[qr*132+tid] + obuf[(8+qr)*132+tid]) / stl[qr];
      size_t row = (size_t)(b*T_ + qt0+qr)*D_ + h*HD_ + d;
      ushort hi, lo;
      fsplit(tot, hi, lo);
      O[(size_t)(comp*2)*PSo + row]   = hi;
      O[(size_t)(comp*2+1)*PSo + row] = lo;
    }
  }
}

// out = z + h * (g/(|g|+1e-8)); h from split-4 planes (1M stride), g fp32.
__global__ __launch_bounds__(256) void gate_kernel(
    const float* __restrict__ z, const ushort* __restrict__ hB,
    const float* __restrict__ gF, float* __restrict__ out, int off)
{
  size_t idx = (size_t)blockIdx.x*256 + threadIdx.x;  // 0..1M
  const size_t M1 = (size_t)1<<20;
  float hr = b2f(hB[idx])      + b2f(hB[M1+idx]);
  float hi = b2f(hB[2*M1+idx]) + b2f(hB[3*M1+idx]);
  float gr = gF[idx], gi = gF[M1+idx];
  float gn = sqrtf(gr*gr + gi*gi) + 1e-8f;
  float pr = (hr*gr - hi*gi) / gn;
  float pi = (hr*gi + hi*gr) / gn;
  size_t zoff = (size_t)off + idx;
  out[zoff]    = z[zoff] + pr;
  out[PL+zoff] = z[PL+zoff] + pi;
}

extern "C" void kernel_launch(void* const* d_in, const int* in_sizes, int n_in,
                              void* d_out, int out_size, void* d_ws, size_t ws_size,
                              hipStream_t stream)
{
  const float* x  = (const float*)d_in[0];
  const float* wq = (const float*)d_in[2];
  const float* bq = (const float*)d_in[3];
  const float* wk = (const float*)d_in[4];
  const float* bk = (const float*)d_in[5];
  const float* wv = (const float*)d_in[6];
  const float* bv = (const float*)d_in[7];
  const float* wo = (const float*)d_in[8];
  const float* bo = (const float*)d_in[9];
  const float* wf1= (const float*)d_in[10];
  const float* bf1= (const float*)d_in[11];
  const float* wf2= (const float*)d_in[12];
  const float* bf2= (const float*)d_in[13];
  const float* wg = (const float*)d_in[14];
  const float* bg = (const float*)d_in[15];
  const float* g1 = (const float*)d_in[16];
  const float* b1 = (const float*)d_in[17];
  const float* g2 = (const float*)d_in[18];
  const float* b2 = (const float*)d_in[19];
  float* out = (float*)d_out;
  char* w8 = (char*)d_ws;
  const size_t MB = (size_t)1<<20;
  const long M1 = 1L<<20, M2 = 1L<<21, M4 = 1L<<22;

  // ---- phased 160MB overlay ----
  ushort* wqkvB = (ushort*)(w8);             // [3][4][1M] us, 24MB
  ushort* woB   = (ushort*)(w8 + 24*MB);     // [4][1M] us, 8MB
  ushort* nzB   = (ushort*)(w8 + 32*MB);     // [4][4M] us, 32MB
  float*  qkvF  = (float*)(w8 + 64*MB);      // [3][2][2M] f32, 48MB (chunk)
  ushort* oBc   = (ushort*)(w8 + 112*MB);    // [4][2M] us, 16MB (chunk)
  float*  z     = (float*)(w8 + 128*MB);     // [2][4M] f32, 32MB
  // FFN-phase overlays:
  ushort* wf2B  = (ushort*)(w8);             // 32MB (over wqkvB+woB)
  ushort* h1c   = (ushort*)(w8 + 32*MB);     // [4][4M] us (over nzB)
  ushort* wf1B  = (ushort*)(w8 + 64*MB);     // 32MB (over qkvF)
  ushort* wgB   = (ushort*)(w8 + 96*MB);     // 8MB
  ushort* nz2c  = (ushort*)(w8 + 104*MB);    // [4][1M] us
  ushort* hBc   = (ushort*)(w8 + 112*MB);    // [4][1M] us (over oBc)
  float*  gFc   = (float*)(w8 + 120*MB);     // [2][1M] f32

  dim3 blk(256);
  // ---- attention-branch weights ----
  cvt_split<<<1024, blk, 0, stream>>>(wq, wqkvB,        M1);
  cvt_split<<<1024, blk, 0, stream>>>(wk, wqkvB + 4*M1, M1);
  cvt_split<<<1024, blk, 0, stream>>>(wv, wqkvB + 8*M1, M1);
  cvt_split<<<1024, blk, 0, stream>>>(wo, woB,          M1);
  cln_kernel<<<dim3(BT_,2), blk, 0, stream>>>(x, (long)PL, 0, g1, b1, nzB, M4);
  for (int cb=0; cb<2; cb++){
    size_t co = (size_t)cb*2048*1024;
    cgemm_split<128,128,64,64><<<dim3(8,16,3), blk, 0, stream>>>(
        nzB + co, M4, wqkvB, M1, 4*M1, bq, bk, bv,
        nullptr, nullptr, qkvF, M2, 2*M2, nullptr, 0,
        2048, 1024, 1024, 0);
    rope_kernel<<<8192, blk, 0, stream>>>(qkvF, qkvF + 2*M2, M2);
    attn_kernel<<<dim3(32,128), blk, 0, stream>>>(qkvF, qkvF + 2*M2, qkvF + 4*M2, M2,
                                                  oBc, M2);
    cgemm_split<64,64,32,32><<<dim3(16,32), blk, 0, stream>>>(
        oBc, M2, woB, M1, 0, bo, bo, bo,
        x + co, x + PL + co, z + co, (long)PL, 0, nullptr, 0,
        2048, 1024, 1024, 0);
  }
  // ---- FFN weights (overlay regions now dead) ----
  cvt_split<<<4096, blk, 0, stream>>>(wf1, wf1B, M4);
  cvt_split<<<4096, blk, 0, stream>>>(wf2, wf2B, M4);
  cvt_split<<<1024, blk, 0, stream>>>(wg, wgB, M1);
  for (int c=0; c<4; c++){
    cln_kernel<<<dim3(1024,2), blk, 0, stream>>>(z, (long)PL, c*1024, g2, b2, nz2c, M1);
    cgemm_split<128,128,64,64><<<dim3(32,8), blk, 0, stream>>>(
        nz2c, M1, wf1B, M4, 0, bf1, bf1, bf1,
        nullptr, nullptr, nullptr, 0, 0, h1c, M4,
        1024, 4096, 1024, 1);
    cgemm_split<64,64,32,32><<<dim3(16,16), blk, 0, stream>>>(
        h1c, M4, wf2B, M4, 0, bf2, bf2, bf2,
        nullptr, nullptr, nullptr, 0, 0, hBc, M1,
        1024, 1024, 4096, 0);
    cgemm_split<64,64,32,32><<<dim3(16,16), blk, 0, stream>>>(
        hBc, M1, wgB, M1, 0, bg, bg, bg,
        nullptr, nullptr, gFc, M1, 0, nullptr, 0,
        1024, 1024, 1024, 0);
    gate_kernel<<<4096, blk, 0, stream>>>(z + (size_t)c*M1 - (size_t)c*M1, hBc, gFc, out, c*(int)M1);
  }
}